// Round 7
// baseline (530.373 us; speedup 1.0000x reference)
//
#include <hip/hip_runtime.h>
#include <hip/hip_cooperative_groups.h>

namespace cg = cooperative_groups;

// Problem constants (from reference)
#define N_NODES 16384
#define D_EMB   128
#define LIST_CAP 1024          // max common neighbors (max degree ~200 incl. i==j)
#define BM_U64   256           // u64 words per compressed row (2 KB)
#define FLAG_OFF N_NODES       // int index of layout flag, right after used_flags
#define BM_OFF_BYTES (1 << 17) // bitmaps start at 128 KiB into ws
#define WS_NEEDED (BM_OFF_BYTES + (size_t)N_NODES * (BM_U64 * 8)) // ~33.7 MB
#define NBLOCKS 1024           // 4 blocks/CU on 256 CUs -> cooperative-safe

// ---------------------------------------------------------------------------
// Fused pipeline: zero+probe -> mark -> compress -> link, one cooperative
// launch, grid.sync() between phases (removes 3 kernel launch/drain
// boundaries and provides device-scope visibility fences).
__global__ __launch_bounds__(256, 4) void ncn_fused(
    const int* __restrict__ links,            // [n_links][2] int32
    const void* __restrict__ adjv,            // [N][N] bool, int32 OR byte encoded
    const float* __restrict__ emb,            // [N][128] fp32
    float* __restrict__ out,                  // [n_links][256] fp32
    int* __restrict__ flags,                  // ws: used flags + layout flag
    unsigned long long* __restrict__ bm64,    // ws: bitmaps [N][256] u64
    int n_links)
{
    cg::grid_group grid = cg::this_grid();
    const int t = threadIdx.x;
    const int b = blockIdx.x;
    const int gtid = b * 256 + t;

    // ---- Phase A0: zero used-flags; block 0 probes adjacency encoding.
    // int32-bool: first 16384 u32 words all in {0,1}; byte-bool: some word >1.
    if (gtid < N_NODES) flags[gtid] = 0;
    if (b == 0) {
        if (t == 0) flags[FLAG_OFF] = 0;
        __syncthreads();
        const unsigned int* words = (const unsigned int*)adjv;
        int any = 0;
        for (int k = t; k < 16384; k += 256)
            if (words[k] > 1u) any = 1;
        if (any) atomicOr(&flags[FLAG_OFF], 1);   // 1 => byte layout
    }
    grid.sync();

    // ---- Phase A1: mark rows referenced by any link endpoint.
    if (gtid < 2 * n_links) flags[links[gtid]] = 1;
    grid.sync();

    // ---- Phase B: compress used rows to 2KB bitmaps.
    const int byte_layout = flags[FLAG_OFF];
    if (!byte_layout) {
        // int32 layout: streaming pack (barrier-free, one 8B store/thread/row).
        // u64[t] bit b <-> node ((b>>2)<<10) + (t<<2) + (b&3).
        for (int r = b; r < N_NODES; r += NBLOCKS) {
            if (!flags[r]) continue;
            const uint4* row = reinterpret_cast<const uint4*>(
                (const int*)adjv + (size_t)r * N_NODES);
            unsigned int lo = 0u, hi = 0u;
#pragma unroll
            for (int k = 0; k < 8; ++k) {
                const uint4 v = row[k * 256 + t];
                const unsigned int nib = min(v.x, 1u) | (min(v.y, 1u) << 1)
                                       | (min(v.z, 1u) << 2) | (min(v.w, 1u) << 3);
                lo |= nib << (4 * k);
            }
#pragma unroll
            for (int k = 8; k < 16; ++k) {
                const uint4 v = row[k * 256 + t];
                const unsigned int nib = min(v.x, 1u) | (min(v.y, 1u) << 1)
                                       | (min(v.z, 1u) << 2) | (min(v.w, 1u) << 3);
                hi |= nib << (4 * (k - 8));
            }
            bm64[(size_t)r * BM_U64 + t] = ((unsigned long long)hi << 32) | lo;
        }
    } else {
        // byte layout (defensive): thread t packs nodes [64t, 64t+64),
        // LINEAR layout: u64[t] bit b <-> node 64t + b.
        for (int r = b; r < N_NODES; r += NBLOCKS) {
            if (!flags[r]) continue;
            const uint4* row = reinterpret_cast<const uint4*>(
                (const unsigned char*)adjv + (size_t)r * N_NODES);
            unsigned long long bits = 0ull;
#pragma unroll
            for (int q = 0; q < 4; ++q) {
                const uint4 v = row[t * 4 + q];
                const unsigned int arr[4] = {v.x, v.y, v.z, v.w};
#pragma unroll
                for (int a = 0; a < 4; ++a)
#pragma unroll
                    for (int bb = 0; bb < 4; ++bb)
                        if ((arr[a] >> (8 * bb)) & 0xFFu)
                            bits |= 1ull << (q * 16 + a * 4 + bb);
            }
            bm64[(size_t)r * BM_U64 + t] = bits;
        }
    }
    grid.sync();

    // ---- Phase C: per link, u64-AND the two bitmaps, decode CN indices,
    // write [product(128) | cn_sum(128)].
    __shared__ int s_list[LIST_CAP];
    __shared__ int s_count;

    for (int link = b; link < n_links; link += NBLOCKS) {
        const int i = links[2 * link];
        const int j = links[2 * link + 1];

        __syncthreads();                 // protect s_list/s_count reuse
        if (t == 0) s_count = 0;
        __syncthreads();

        unsigned long long m = bm64[(size_t)i * BM_U64 + t]
                             & bm64[(size_t)j * BM_U64 + t];
        while (m) {
            const int bit = __ffsll(m) - 1;
            m &= m - 1;
            const int node = byte_layout
                ? (t * 64 + bit)
                : (((bit >> 2) << 10) + (t << 2) + (bit & 3));
            const int pos = atomicAdd(&s_count, 1);
            if (pos < LIST_CAP) s_list[pos] = node;
        }
        __syncthreads();

        int count = s_count;
        if (count > LIST_CAP) count = LIST_CAP;

        const size_t obase = (size_t)link * (2 * D_EMB);
        if (t < D_EMB) {
            out[obase + t] = emb[(size_t)i * D_EMB + t]
                           * emb[(size_t)j * D_EMB + t];
        } else {
            const int d = t - D_EMB;
            float s = 0.0f;
            for (int c = 0; c < count; ++c)
                s += emb[(size_t)s_list[c] * D_EMB + d];
            out[obase + D_EMB + d] = s;
        }
    }
}

// ---------------------------------------------------------------------------
// Fallback (ws too small): direct kernel — reads both full rows per link.
__global__ __launch_bounds__(256) void detect_layout_kernel(
    const unsigned int* __restrict__ words, int* __restrict__ flag)
{
    __shared__ int s_any;
    if (threadIdx.x == 0) s_any = 0;
    __syncthreads();
    int any = 0;
    for (int k = threadIdx.x; k < 16384; k += 256)
        if (words[k] > 1u) any = 1;
    if (any) atomicOr(&s_any, 1);
    __syncthreads();
    if (threadIdx.x == 0) *flag = s_any;
}

__global__ __launch_bounds__(256) void ncn_direct(
    const int* __restrict__ links, const void* __restrict__ adjv,
    const float* __restrict__ emb, float* __restrict__ out,
    const int* __restrict__ flag, int n_links)
{
    const int link = blockIdx.x;
    if (link >= n_links) return;
    const int i = links[2 * link];
    const int j = links[2 * link + 1];

    __shared__ int s_list[LIST_CAP];
    __shared__ int s_count;
    if (threadIdx.x == 0) s_count = 0;
    __syncthreads();

    const int byte_layout = flag ? flag[0] : 0;
    if (byte_layout) {
        const uint4* rowi = reinterpret_cast<const uint4*>(
            (const unsigned char*)adjv + (size_t)i * N_NODES);
        const uint4* rowj = reinterpret_cast<const uint4*>(
            (const unsigned char*)adjv + (size_t)j * N_NODES);
#pragma unroll
        for (int c = 0; c < 4; ++c) {
            const int idx = c * 256 + threadIdx.x;
            const uint4 a = rowi[idx];
            const uint4 bq = rowj[idx];
            unsigned int m[4] = {a.x & bq.x, a.y & bq.y, a.z & bq.z, a.w & bq.w};
            if (m[0] | m[1] | m[2] | m[3]) {
                const int base = idx * 16;
#pragma unroll
                for (int w = 0; w < 4; ++w) {
                    unsigned int v = m[w];
                    if (!v) continue;
#pragma unroll
                    for (int b8 = 0; b8 < 4; ++b8) {
                        if ((v >> (8 * b8)) & 0xFFu) {
                            int pos = atomicAdd(&s_count, 1);
                            if (pos < LIST_CAP) s_list[pos] = base + w * 4 + b8;
                        }
                    }
                }
            }
        }
    } else {
        const uint4* rowi = reinterpret_cast<const uint4*>(
            (const int*)adjv + (size_t)i * N_NODES);
        const uint4* rowj = reinterpret_cast<const uint4*>(
            (const int*)adjv + (size_t)j * N_NODES);
#pragma unroll
        for (int c = 0; c < 16; ++c) {
            const int idx = c * 256 + threadIdx.x;
            const uint4 a = rowi[idx];
            const uint4 bq = rowj[idx];
            const int base = idx * 4;
            if (a.x & bq.x) { int p = atomicAdd(&s_count, 1); if (p < LIST_CAP) s_list[p] = base + 0; }
            if (a.y & bq.y) { int p = atomicAdd(&s_count, 1); if (p < LIST_CAP) s_list[p] = base + 1; }
            if (a.z & bq.z) { int p = atomicAdd(&s_count, 1); if (p < LIST_CAP) s_list[p] = base + 2; }
            if (a.w & bq.w) { int p = atomicAdd(&s_count, 1); if (p < LIST_CAP) s_list[p] = base + 3; }
        }
    }
    __syncthreads();

    int count = s_count;
    if (count > LIST_CAP) count = LIST_CAP;

    const int t = threadIdx.x;
    const size_t obase = (size_t)link * (2 * D_EMB);
    if (t < D_EMB) {
        out[obase + t] = emb[(size_t)i * D_EMB + t] * emb[(size_t)j * D_EMB + t];
    } else {
        const int d = t - D_EMB;
        float s = 0.0f;
        for (int c = 0; c < count; ++c)
            s += emb[(size_t)s_list[c] * D_EMB + d];
        out[obase + D_EMB + d] = s;
    }
}

extern "C" void kernel_launch(void* const* d_in, const int* in_sizes, int n_in,
                              void* d_out, int out_size, void* d_ws, size_t ws_size,
                              hipStream_t stream) {
    const int* links = (const int*)d_in[0];     // int32 [n_links][2]
    const void* adj = d_in[1];                  // bool matrix (encoding probed)
    const float* emb = (const float*)d_in[2];   // fp32 [N_NODES][D_EMB]
    float* out = (float*)d_out;

    const int n_links = in_sizes[0] / 2;

    if (ws_size >= WS_NEEDED) {
        int* flags = (int*)d_ws;
        unsigned long long* bm64 =
            (unsigned long long*)((char*)d_ws + BM_OFF_BYTES);

        void* args[] = {
            (void*)&links, (void*)&adj, (void*)&emb, (void*)&out,
            (void*)&flags, (void*)&bm64, (void*)&n_links
        };
        hipLaunchCooperativeKernel((const void*)ncn_fused,
                                   dim3(NBLOCKS), dim3(256),
                                   args, 0, stream);
    } else {
        int* flag = (ws_size >= sizeof(int)) ? (int*)d_ws : nullptr;
        if (flag) detect_layout_kernel<<<1, 256, 0, stream>>>(
            (const unsigned int*)adj, flag);
        ncn_direct<<<n_links, 256, 0, stream>>>(links, adj, emb, out, flag, n_links);
    }
}

// Round 8
// 178.051 us; speedup vs baseline: 2.9788x; 2.9788x over previous
//
#include <hip/hip_runtime.h>

// Problem constants (from reference)
#define N_NODES 16384
#define D_EMB   128
#define LIST_CAP 1024          // max common neighbors (max degree ~200 incl. i==j)
#define BM_U64   256           // u64 words per compressed row (2 KB)
#define FLAG_OFF N_NODES       // int index of layout flag, right after claim flags
#define BM_OFF_BYTES (1 << 17) // bitmaps start at 128 KiB into ws
#define WS_NEEDED (BM_OFF_BYTES + (size_t)N_NODES * (BM_U64 * 8)) // ~33.7 MB

// ---------------------------------------------------------------------------
// Pass 1 (init): blocks 0..63 zero the claim flags; block 64 probes the
// adjacency encoding. int32-bool: first 16384 u32 words all in {0,1};
// byte-bool: some word >1 w.p. ~1.
__global__ __launch_bounds__(256) void init_kernel(
    const unsigned int* __restrict__ words, int* __restrict__ flags)
{
    if (blockIdx.x < 64) {
        flags[blockIdx.x * 256 + threadIdx.x] = 0;
    } else {
        __shared__ int s_any;
        if (threadIdx.x == 0) s_any = 0;
        __syncthreads();
        int any = 0;
        for (int k = threadIdx.x; k < 16384; k += 256)
            if (words[k] > 1u) any = 1;
        if (any) atomicOr(&s_any, 1);
        __syncthreads();
        if (threadIdx.x == 0) flags[FLAG_OFF] = s_any;  // 1 => byte layout
    }
}

// Pass 2 (claim + compress): one block per link ENDPOINT. Block claims its
// row via atomicCAS (dedup fused into compress — no separate mark pass);
// winner compresses the row to a 2KB bitmap with the R6 streaming pack
// (barrier-free, no LDS, one coalesced 8B store per thread).
// int32 layout, PERMUTED: u64[t] bit b <-> node 1024*(b>>2) + 4*t + (b&3).
// byte layout, LINEAR: u64[t] bit b <-> node 64*t + b.
__global__ __launch_bounds__(256) void claim_compress_kernel(
    const int* __restrict__ links, const void* __restrict__ adjv,
    int* __restrict__ flags, unsigned long long* __restrict__ bm64,
    int n_endpoints)
{
    const int e = blockIdx.x;
    if (e >= n_endpoints) return;
    const int r = links[e];

    // One thread claims; whole block abides by the result.
    __shared__ int s_claimed;
    if (threadIdx.x == 0)
        s_claimed = (atomicCAS(&flags[r], 0, 1) == 0) ? 1 : 0;
    __syncthreads();
    if (!s_claimed) return;

    const int t = threadIdx.x;
    const int byte_layout = flags[FLAG_OFF];

    if (!byte_layout) {
        const uint4* row = reinterpret_cast<const uint4*>(
            (const int*)adjv + (size_t)r * N_NODES);
        unsigned int lo = 0u, hi = 0u;
#pragma unroll
        for (int k = 0; k < 8; ++k) {
            const uint4 v = row[k * 256 + t];
            const unsigned int nib = min(v.x, 1u) | (min(v.y, 1u) << 1)
                                   | (min(v.z, 1u) << 2) | (min(v.w, 1u) << 3);
            lo |= nib << (4 * k);
        }
#pragma unroll
        for (int k = 8; k < 16; ++k) {
            const uint4 v = row[k * 256 + t];
            const unsigned int nib = min(v.x, 1u) | (min(v.y, 1u) << 1)
                                   | (min(v.z, 1u) << 2) | (min(v.w, 1u) << 3);
            hi |= nib << (4 * (k - 8));
        }
        bm64[(size_t)r * BM_U64 + t] = ((unsigned long long)hi << 32) | lo;
    } else {
        const uint4* row = reinterpret_cast<const uint4*>(
            (const unsigned char*)adjv + (size_t)r * N_NODES);
        unsigned long long bits = 0ull;
#pragma unroll
        for (int q = 0; q < 4; ++q) {
            const uint4 v = row[t * 4 + q];
            const unsigned int arr[4] = {v.x, v.y, v.z, v.w};
#pragma unroll
            for (int a = 0; a < 4; ++a)
#pragma unroll
                for (int bb = 0; bb < 4; ++bb)
                    if ((arr[a] >> (8 * bb)) & 0xFFu)
                        bits |= 1ull << (q * 16 + a * 4 + bb);
        }
        bm64[(size_t)r * BM_U64 + t] = bits;
    }
}

// Pass 3 (link): per link, one u64 AND per thread covers the whole row pair,
// decode set bits -> node indices, write [product(128) | cn_sum(128)].
__global__ __launch_bounds__(256) void link_kernel(
    const int* __restrict__ links, const unsigned long long* __restrict__ bm64,
    const float* __restrict__ emb, float* __restrict__ out,
    const int* __restrict__ flags, int n_links)
{
    const int link = blockIdx.x;
    if (link >= n_links) return;
    const int i = links[2 * link];
    const int j = links[2 * link + 1];
    const int byte_layout = flags[FLAG_OFF];

    __shared__ int s_list[LIST_CAP];
    __shared__ int s_count;
    if (threadIdx.x == 0) s_count = 0;
    __syncthreads();

    const int t = threadIdx.x;
    unsigned long long m = bm64[(size_t)i * BM_U64 + t]
                         & bm64[(size_t)j * BM_U64 + t];
    while (m) {
        const int b = __ffsll(m) - 1;
        m &= m - 1;
        const int node = byte_layout
            ? (t * 64 + b)
            : (((b >> 2) << 10) + (t << 2) + (b & 3));
        const int pos = atomicAdd(&s_count, 1);
        if (pos < LIST_CAP) s_list[pos] = node;
    }
    __syncthreads();

    int count = s_count;
    if (count > LIST_CAP) count = LIST_CAP;

    const size_t obase = (size_t)link * (2 * D_EMB);
    if (t < D_EMB) {
        out[obase + t] = emb[(size_t)i * D_EMB + t] * emb[(size_t)j * D_EMB + t];
    } else {
        const int d = t - D_EMB;
        float s = 0.0f;
        for (int c = 0; c < count; ++c)
            s += emb[(size_t)s_list[c] * D_EMB + d];
        out[obase + D_EMB + d] = s;
    }
}

// ---------------------------------------------------------------------------
// Fallback (ws too small): direct kernel — reads both full rows per link.
__global__ __launch_bounds__(256) void detect_layout_kernel(
    const unsigned int* __restrict__ words, int* __restrict__ flag)
{
    __shared__ int s_any;
    if (threadIdx.x == 0) s_any = 0;
    __syncthreads();
    int any = 0;
    for (int k = threadIdx.x; k < 16384; k += 256)
        if (words[k] > 1u) any = 1;
    if (any) atomicOr(&s_any, 1);
    __syncthreads();
    if (threadIdx.x == 0) *flag = s_any;
}

__global__ __launch_bounds__(256) void ncn_direct(
    const int* __restrict__ links, const void* __restrict__ adjv,
    const float* __restrict__ emb, float* __restrict__ out,
    const int* __restrict__ flag, int n_links)
{
    const int link = blockIdx.x;
    if (link >= n_links) return;
    const int i = links[2 * link];
    const int j = links[2 * link + 1];

    __shared__ int s_list[LIST_CAP];
    __shared__ int s_count;
    if (threadIdx.x == 0) s_count = 0;
    __syncthreads();

    const int byte_layout = flag ? flag[0] : 0;
    if (byte_layout) {
        const uint4* rowi = reinterpret_cast<const uint4*>(
            (const unsigned char*)adjv + (size_t)i * N_NODES);
        const uint4* rowj = reinterpret_cast<const uint4*>(
            (const unsigned char*)adjv + (size_t)j * N_NODES);
#pragma unroll
        for (int c = 0; c < 4; ++c) {
            const int idx = c * 256 + threadIdx.x;
            const uint4 a = rowi[idx];
            const uint4 bq = rowj[idx];
            unsigned int m[4] = {a.x & bq.x, a.y & bq.y, a.z & bq.z, a.w & bq.w};
            if (m[0] | m[1] | m[2] | m[3]) {
                const int base = idx * 16;
#pragma unroll
                for (int w = 0; w < 4; ++w) {
                    unsigned int v = m[w];
                    if (!v) continue;
#pragma unroll
                    for (int b8 = 0; b8 < 4; ++b8) {
                        if ((v >> (8 * b8)) & 0xFFu) {
                            int pos = atomicAdd(&s_count, 1);
                            if (pos < LIST_CAP) s_list[pos] = base + w * 4 + b8;
                        }
                    }
                }
            }
        }
    } else {
        const uint4* rowi = reinterpret_cast<const uint4*>(
            (const int*)adjv + (size_t)i * N_NODES);
        const uint4* rowj = reinterpret_cast<const uint4*>(
            (const int*)adjv + (size_t)j * N_NODES);
#pragma unroll
        for (int c = 0; c < 16; ++c) {
            const int idx = c * 256 + threadIdx.x;
            const uint4 a = rowi[idx];
            const uint4 bq = rowj[idx];
            const int base = idx * 4;
            if (a.x & bq.x) { int p = atomicAdd(&s_count, 1); if (p < LIST_CAP) s_list[p] = base + 0; }
            if (a.y & bq.y) { int p = atomicAdd(&s_count, 1); if (p < LIST_CAP) s_list[p] = base + 1; }
            if (a.z & bq.z) { int p = atomicAdd(&s_count, 1); if (p < LIST_CAP) s_list[p] = base + 2; }
            if (a.w & bq.w) { int p = atomicAdd(&s_count, 1); if (p < LIST_CAP) s_list[p] = base + 3; }
        }
    }
    __syncthreads();

    int count = s_count;
    if (count > LIST_CAP) count = LIST_CAP;

    const int t = threadIdx.x;
    const size_t obase = (size_t)link * (2 * D_EMB);
    if (t < D_EMB) {
        out[obase + t] = emb[(size_t)i * D_EMB + t] * emb[(size_t)j * D_EMB + t];
    } else {
        const int d = t - D_EMB;
        float s = 0.0f;
        for (int c = 0; c < count; ++c)
            s += emb[(size_t)s_list[c] * D_EMB + d];
        out[obase + D_EMB + d] = s;
    }
}

extern "C" void kernel_launch(void* const* d_in, const int* in_sizes, int n_in,
                              void* d_out, int out_size, void* d_ws, size_t ws_size,
                              hipStream_t stream) {
    const int* links = (const int*)d_in[0];     // int32 [n_links][2]
    const void* adj = d_in[1];                  // bool matrix (encoding probed)
    const float* emb = (const float*)d_in[2];   // fp32 [N_NODES][D_EMB]
    float* out = (float*)d_out;

    const int n_links = in_sizes[0] / 2;

    if (ws_size >= WS_NEEDED) {
        int* flags = (int*)d_ws;
        unsigned long long* bm64 =
            (unsigned long long*)((char*)d_ws + BM_OFF_BYTES);

        init_kernel<<<65, 256, 0, stream>>>((const unsigned int*)adj, flags);
        claim_compress_kernel<<<2 * n_links, 256, 0, stream>>>(
            links, adj, flags, bm64, 2 * n_links);
        link_kernel<<<n_links, 256, 0, stream>>>(
            links, bm64, emb, out, flags, n_links);
    } else {
        int* flag = (ws_size >= sizeof(int)) ? (int*)d_ws : nullptr;
        if (flag) detect_layout_kernel<<<1, 256, 0, stream>>>(
            (const unsigned int*)adj, flag);
        ncn_direct<<<n_links, 256, 0, stream>>>(links, adj, emb, out, flag, n_links);
    }
}